// Round 5
// baseline (420.384 us; speedup 1.0000x reference)
//
#include <hip/hip_runtime.h>
#include <math.h>

#define B_ 128
#define NTOK 577
#define P_ 576
#define D_ 768
#define G_ 17
#define KOCC 10
#define INV_TEMP 10.0f
#define U17 (1.0f / 17.0f)
#define NPART 9

// ws layout (float offsets):
#define OFF_WT 0                                // [17][768] transposed weights
#define OFF_SIM (G_ * D_)                       // [B][576] (unnormalized-by-cls sim)
#define OFF_OCC (OFF_SIM + B_ * P_)             // [B][10] ints
#define OFF_GFP (OFF_OCC + B_ * KOCC)           // [NPART][B][17][768] partials
#define GFP_SLAB ((size_t)B_ * G_ * D_)

// K0a: transpose gw (D,G) -> wt (G,D). 17 blocks.
__global__ __launch_bounds__(256) void k0_wt(const float* __restrict__ gw,
                                             float* __restrict__ wt) {
    int g = blockIdx.x;
    for (int d = threadIdx.x; d < D_; d += 256)
        wt[g * D_ + d] = gw[d * G_ + g];
}

// K0b (atomic-fallback only): zero feats group rows.
__global__ __launch_bounds__(256) void k0_zero(float* __restrict__ feats) {
    int b = blockIdx.x;
    float4 z = {0.f, 0.f, 0.f, 0.f};
    float4* fb = (float4*)(feats + (size_t)b * 18 * D_ + D_);
    for (int i = threadIdx.x; i < G_ * D_ / 4; i += 256) fb[i] = z;
}

// K13: fused scores + softmax + attn + sim + group-feature partial.
// grid (9, B_), block 256 (4 waves). Block = 64 patches.
// Phase A: register-tiled scores (lane owns 4 patches x 16-lane k-slice);
//          wt+cls double-buffered in LDS per 64-dim chunk.
// Softmax: thread p<64 normalizes its column, writes attn (global) + atile (LDS).
// Phase B: threads 0..191 own a d-float4; rank-64 update from the L2-hot x tile
//          with attn broadcast from LDS; private gfp slab store (no atomics).
__global__ __launch_bounds__(256) void k13_fused(const float* __restrict__ x,
                                                 const float* __restrict__ wt,
                                                 float* __restrict__ sim,
                                                 float* __restrict__ attn,
                                                 float* __restrict__ gfp,
                                                 float* __restrict__ feats) {
    __shared__ __align__(16) float buf[2][18 * 64];
    __shared__ __align__(16) float atile[19 * 68];   // rows 0..16 scores->attn, 17 clsdot, 18 sumsq
    int tid = threadIdx.x;
    int b = blockIdx.y, chunk = blockIdx.x;
    const float* clsrow = x + (size_t)b * NTOK * D_;

    for (int i = tid; i < 288; i += 256) {
        int r = i >> 4, c = i & 15;
        const float* src = (r < 17) ? (wt + r * D_ + c * 4) : (clsrow + c * 4);
        *(float4*)&buf[0][r * 64 + c * 4] = *(const float4*)src;
    }
    int lane = tid & 63, wave = tid >> 6;
    int lr = lane & 15, row4 = lane >> 4;
    int pbase = wave * 16 + row4 * 4;
    const float* xp0 = x + ((size_t)(b * NTOK + 1 + chunk * 64 + pbase)) * D_ + lr * 4;

    float4 xv[4], xn[4];
    #pragma unroll
    for (int m = 0; m < 4; ++m) xv[m] = *(const float4*)(xp0 + (size_t)m * D_);

    float s[19][4];
    #pragma unroll
    for (int i = 0; i < 19; ++i)
        #pragma unroll
        for (int m = 0; m < 4; ++m) s[i][m] = 0.f;
    __syncthreads();

    for (int kc = 0; kc < 12; ++kc) {
        int cb = kc & 1, nb = cb ^ 1;
        if (kc < 11) {
            #pragma unroll
            for (int m = 0; m < 4; ++m)
                xn[m] = *(const float4*)(xp0 + (kc + 1) * 64 + (size_t)m * D_);
            for (int i = tid; i < 288; i += 256) {
                int r = i >> 4, c = i & 15;
                const float* src = (r < 17) ? (wt + r * D_ + (kc + 1) * 64 + c * 4)
                                            : (clsrow + (kc + 1) * 64 + c * 4);
                *(float4*)&buf[nb][r * 64 + c * 4] = *(const float4*)src;
            }
        }
        #pragma unroll
        for (int g = 0; g < 18; ++g) {
            float4 w4 = *(const float4*)&buf[cb][g * 64 + lr * 4];
            #pragma unroll
            for (int m = 0; m < 4; ++m)
                s[g][m] = fmaf(xv[m].x, w4.x, fmaf(xv[m].y, w4.y,
                          fmaf(xv[m].z, w4.z, fmaf(xv[m].w, w4.w, s[g][m]))));
        }
        #pragma unroll
        for (int m = 0; m < 4; ++m)
            s[18][m] = fmaf(xv[m].x, xv[m].x, fmaf(xv[m].y, xv[m].y,
                       fmaf(xv[m].z, xv[m].z, fmaf(xv[m].w, xv[m].w, s[18][m]))));
        #pragma unroll
        for (int m = 0; m < 4; ++m) xv[m] = xn[m];
        __syncthreads();
    }

    #pragma unroll
    for (int off = 8; off >= 1; off >>= 1)
        #pragma unroll
        for (int i = 0; i < 19; ++i)
            #pragma unroll
            for (int m = 0; m < 4; ++m)
                s[i][m] += __shfl_xor(s[i][m], off, 16);

    #pragma unroll
    for (int g = 0; g < 19; ++g) {
        if (lr == ((g < 16) ? g : 15)) {
            float4 v = {s[g][0], s[g][1], s[g][2], s[g][3]};
            *(float4*)&atile[g * 68 + pbase] = v;
        }
    }
    __syncthreads();

    if (tid < 64) {
        int p = chunk * 64 + tid;
        float v[17];
        float mx = -3.0e38f;
        #pragma unroll
        for (int g = 0; g < 17; ++g) {
            v[g] = atile[g * 68 + tid];
            mx = fmaxf(mx, v[g]);
        }
        float tot = 0.f;
        #pragma unroll
        for (int g = 0; g < 17; ++g) {
            v[g] = __expf((v[g] - mx) * INV_TEMP);
            tot += v[g];
        }
        float inv = 1.0f / tot;
        float* ap = attn + ((size_t)b * G_) * P_ + p;
        #pragma unroll
        for (int g = 0; g < 17; ++g) {
            float a = v[g] * inv;
            ap[(size_t)g * P_] = a;          // global (unmasked; k4 patches occ cols)
            atile[g * 68 + tid] = a;         // LDS for Phase B
        }
        float cd = atile[17 * 68 + tid];
        float sq = atile[18 * 68 + tid];
        sim[(size_t)b * P_ + p] = cd / fmaxf(sqrtf(sq), 1e-12f);  // cls-norm dropped: rank-equivalent
    }
    __syncthreads();

    // ---- Phase B: rank-64 update from L2-hot x tile ----
    if (tid < 192) {
        const float* xb = x + ((size_t)(b * NTOK + 1 + chunk * 64)) * D_ + tid * 4;
        float4 acc[G_];
        #pragma unroll
        for (int g = 0; g < G_; ++g) acc[g] = make_float4(0.f, 0.f, 0.f, 0.f);

        float4 c0 = *(const float4*)(xb + (size_t)0 * D_);
        float4 c1 = *(const float4*)(xb + (size_t)1 * D_);
        float4 c2 = *(const float4*)(xb + (size_t)2 * D_);
        float4 c3 = *(const float4*)(xb + (size_t)3 * D_);
        for (int pp = 0; pp < 64; pp += 4) {
            float4 n0, n1, n2, n3;
            if (pp + 4 < 64) {
                n0 = *(const float4*)(xb + (size_t)(pp + 4) * D_);
                n1 = *(const float4*)(xb + (size_t)(pp + 5) * D_);
                n2 = *(const float4*)(xb + (size_t)(pp + 6) * D_);
                n3 = *(const float4*)(xb + (size_t)(pp + 7) * D_);
            }
            #pragma unroll
            for (int g = 0; g < G_; ++g) {
                float4 a = *(const float4*)&atile[g * 68 + pp];   // wave-uniform broadcast
                acc[g].x = fmaf(a.x, c0.x, fmaf(a.y, c1.x, fmaf(a.z, c2.x, fmaf(a.w, c3.x, acc[g].x))));
                acc[g].y = fmaf(a.x, c0.y, fmaf(a.y, c1.y, fmaf(a.z, c2.y, fmaf(a.w, c3.y, acc[g].y))));
                acc[g].z = fmaf(a.x, c0.z, fmaf(a.y, c1.z, fmaf(a.z, c2.z, fmaf(a.w, c3.z, acc[g].z))));
                acc[g].w = fmaf(a.x, c0.w, fmaf(a.y, c1.w, fmaf(a.z, c2.w, fmaf(a.w, c3.w, acc[g].w))));
            }
            c0 = n0; c1 = n1; c2 = n2; c3 = n3;
        }
        if (gfp) {
            float* gb = gfp + ((size_t)(chunk * B_ + b) * G_) * D_ + tid * 4;
            #pragma unroll
            for (int g = 0; g < G_; ++g) *(float4*)(gb + (size_t)g * D_) = acc[g];
        } else {
            float* fb = feats + ((size_t)(b * 18) + 1) * D_ + tid * 4;
            #pragma unroll
            for (int g = 0; g < G_; ++g) {
                atomicAdd(fb + (size_t)g * D_ + 0, acc[g].x);
                atomicAdd(fb + (size_t)g * D_ + 1, acc[g].y);
                atomicAdd(fb + (size_t)g * D_ + 2, acc[g].z);
                atomicAdd(fb + (size_t)g * D_ + 3, acc[g].w);
            }
        }
    }
}

// K2: per batch (1 wave): 10 smallest sims (ties -> lower index) -> occ_idx.
__global__ __launch_bounds__(64) void k2_occl(const float* __restrict__ sim,
                                              int* __restrict__ occ_idx) {
    int b = blockIdx.x, lane = threadIdx.x;
    int base = lane * 9;
    float v[9];
    #pragma unroll
    for (int j = 0; j < 9; ++j) v[j] = sim[(size_t)b * P_ + base + j];
    for (int t = 0; t < KOCC; ++t) {
        float mv = 3.0e38f;
        int mi = 1 << 30;
        #pragma unroll
        for (int j = 0; j < 9; ++j) {
            if (v[j] < mv) { mv = v[j]; mi = base + j; }
        }
        #pragma unroll
        for (int off = 1; off < 64; off <<= 1) {
            float ov = __shfl_xor(mv, off, 64);
            int oi = __shfl_xor(mi, off, 64);
            if (ov < mv || (ov == mv && oi < mi)) { mv = ov; mi = oi; }
        }
        if (lane == 0) occ_idx[b * KOCC + t] = mi;
        int loc = mi - base;
        if (loc >= 0 && loc < 9) v[loc] = 3.0e38f;
    }
}

// K4: grid (B_), block 192. cls row copy; reduce NPART slabs; subtract
// sum_occ attn_u[g,p]*x[p]; write feats groups; patch attn occ cols to 1/17.
__global__ __launch_bounds__(192) void k4_fin(const float* __restrict__ x,
                                              const int* __restrict__ occ_idx,
                                              const float* __restrict__ gfp,
                                              float* __restrict__ attn,
                                              float* __restrict__ feats,
                                              int nparts) {
    __shared__ float ao[G_ * KOCC];
    __shared__ int op[KOCC];
    int b = blockIdx.x, tid = threadIdx.x;
    if (tid < KOCC) op[tid] = occ_idx[b * KOCC + tid];
    __syncthreads();
    if (tid < G_ * KOCC) {
        int g = tid / KOCC, t = tid - g * KOCC;
        float* ap = attn + ((size_t)b * G_ + g) * P_ + op[t];
        ao[tid] = *ap;        // unmasked attn at occluded column
        *ap = U17;            // patch output (same thread, same addr - no race)
    }
    __syncthreads();

    float* fb = feats + (size_t)b * 18 * D_ + tid * 4;
    *(float4*)fb = *(const float4*)(x + (size_t)b * NTOK * D_ + tid * 4);  // cls row

    float4 acc[G_];
    if (nparts == 0) {
        #pragma unroll
        for (int g = 0; g < G_; ++g)
            acc[g] = *(const float4*)(fb + (size_t)(1 + g) * D_);
    } else {
        #pragma unroll
        for (int g = 0; g < G_; ++g) acc[g] = make_float4(0.f, 0.f, 0.f, 0.f);
        for (int pc = 0; pc < nparts; ++pc) {
            const float* gb = gfp + ((size_t)(pc * B_ + b) * G_) * D_ + tid * 4;
            #pragma unroll
            for (int g = 0; g < G_; ++g) {
                float4 v = *(const float4*)(gb + (size_t)g * D_);
                acc[g].x += v.x; acc[g].y += v.y; acc[g].z += v.z; acc[g].w += v.w;
            }
        }
    }
    for (int t = 0; t < KOCC; ++t) {
        float4 xo = *(const float4*)(x + ((size_t)(b * NTOK) + 1 + op[t]) * D_ + tid * 4);
        #pragma unroll
        for (int g = 0; g < G_; ++g) {
            float a = ao[g * KOCC + t];
            acc[g].x = fmaf(-a, xo.x, acc[g].x);
            acc[g].y = fmaf(-a, xo.y, acc[g].y);
            acc[g].z = fmaf(-a, xo.z, acc[g].z);
            acc[g].w = fmaf(-a, xo.w, acc[g].w);
        }
    }
    #pragma unroll
    for (int g = 0; g < G_; ++g)
        *(float4*)(fb + (size_t)(1 + g) * D_) = acc[g];
}

extern "C" void kernel_launch(void* const* d_in, const int* in_sizes, int n_in,
                              void* d_out, int out_size, void* d_ws, size_t ws_size,
                              hipStream_t stream) {
    const float* x  = (const float*)d_in[0];
    const float* gw = (const float*)d_in[1];
    float* feats = (float*)d_out;                               // B*18*D
    float* attn  = (float*)d_out + (size_t)B_ * 18 * D_;        // B*17*P
    float* wt      = (float*)d_ws + OFF_WT;
    float* sim     = (float*)d_ws + OFF_SIM;
    int*   occ_idx = (int*)((float*)d_ws + OFF_OCC);
    float* gfp     = (float*)d_ws + OFF_GFP;

    bool use_gfp = (OFF_GFP + (size_t)NPART * GFP_SLAB) * 4 <= ws_size;

    k0_wt<<<G_, 256, 0, stream>>>(gw, wt);
    if (!use_gfp) k0_zero<<<B_, 256, 0, stream>>>(feats);
    k13_fused<<<dim3(NPART, B_), 256, 0, stream>>>(x, wt, sim, attn,
                                                   use_gfp ? gfp : nullptr, feats);
    k2_occl<<<B_, 64, 0, stream>>>(sim, occ_idx);
    k4_fin<<<B_, 192, 0, stream>>>(x, occ_idx, gfp, attn, feats,
                                   use_gfp ? NPART : 0);
}